// Round 1
// 738.376 us; speedup vs baseline: 1.1015x; 1.1015x over previous
//
#include <hip/hip_runtime.h>
#include <math.h>

#define B_SZ   16384
#define D_EMB  128
#define D_HID  1024
#define D_FEAT 4096

typedef float f4 __attribute__((ext_vector_type(4)));

// ---------------------------------------------------------------------------
// Kernel A: h[g][m] = relu(ctx_g @ W1_g + b1_g).  grid = 8 blocks (2 gates x 4),
// 256 threads, one h-value per thread, coalesced W1 reads, NO redundancy
// (old kernel recomputed all of stage-1 in every one of 16 blocks per gate).
// ---------------------------------------------------------------------------
__global__ __launch_bounds__(256) void h_kernel(
    const float* __restrict__ ctx1, const float* __restrict__ ctx2,
    const float* __restrict__ W1a,  const float* __restrict__ b1a,
    const float* __restrict__ W1b,  const float* __restrict__ b1b,
    float* __restrict__ h /* [2][D_HID] */)
{
    const int g   = blockIdx.x >> 2;
    const int blk = blockIdx.x & 3;
    const float* ctx = g ? ctx2 : ctx1;
    const float* W1  = g ? W1b  : W1a;
    const float* b1  = g ? b1b  : b1a;

    __shared__ float s_ctx[D_EMB];
    const int t = threadIdx.x;
    if (t < D_EMB) s_ctx[t] = ctx[t];
    __syncthreads();

    const int m = blk * 256 + t;
    float acc = b1[m];
#pragma unroll 8
    for (int i = 0; i < D_EMB; ++i)
        acc = fmaf(s_ctx[i], W1[i * D_HID + m], acc);
    h[g * D_HID + m] = acc > 0.0f ? acc : 0.0f;
}

// ---------------------------------------------------------------------------
// Kernel B: gates[g][j] = sigmoid(h_g @ W2_g[:,j] + b2_g[j]) * 2.
// grid = 256 blocks (2 gates x 128), 256 threads = 32 columns x 8 k-slices.
// Split-K: thread (tj,tk) sums 128 of the 1024 k-terms; LDS reduce.
// 1 block per CU => full-chip per-CU bandwidth instead of 32 CUs.
// ---------------------------------------------------------------------------
__global__ __launch_bounds__(256) void gate_kernel(
    const float* __restrict__ W2a, const float* __restrict__ b2a,
    const float* __restrict__ W2b, const float* __restrict__ b2b,
    const float* __restrict__ h,    /* [2][D_HID] */
    float* __restrict__ gates       /* [2][D_FEAT] */)
{
    const int g   = blockIdx.x >> 7;
    const int blk = blockIdx.x & 127;
    const float* W2 = g ? W2b : W2a;
    const float* b2 = g ? b2b : b2a;

    __shared__ float s_h[D_HID];
    __shared__ float s_part[256];

    const int t = threadIdx.x;
#pragma unroll
    for (int r = 0; r < D_HID / 256; ++r)
        s_h[t + 256 * r] = h[g * D_HID + t + 256 * r];
    __syncthreads();

    const int tj = t & 31;          // column within block's 32-column slab
    const int tk = t >> 5;          // k-slice 0..7
    const int j  = blk * 32 + tj;

    const float* w = W2 + (size_t)(tk * 128) * D_FEAT + j;
    float p = 0.0f;
#pragma unroll 8
    for (int kk = 0; kk < 128; ++kk)
        p = fmaf(s_h[tk * 128 + kk], w[(size_t)kk * D_FEAT], p);

    s_part[tj * 8 + tk] = p;
    __syncthreads();

    if (t < 32) {
        float a = b2[blk * 32 + t];
#pragma unroll
        for (int u = 0; u < 8; ++u) a += s_part[t * 8 + u];
        gates[g * D_FEAT + blk * 32 + t] = 2.0f / (1.0f + expf(-a));
    }
}

// ---------------------------------------------------------------------------
// Kernel C: out1 = emb * g1, out2 = emb * g2.
// 2048 blocks x 256 threads = 524288 threads = 1024 float4-cols x 512 rows.
// Each thread owns ONE column: gates live in registers across all 32 row
// iterations; inner loop = 1 NT load + 2 NT stores, zero gate traffic.
// ---------------------------------------------------------------------------
__global__ __launch_bounds__(256) void mul_kernel(
    const f4* __restrict__ emb,
    const f4* __restrict__ gates,   // [2][D_FEAT/4]
    f4* __restrict__ out1,
    f4* __restrict__ out2)
{
    const int tid = blockIdx.x * 256 + threadIdx.x;   // 0..524287
    const int c   = tid & (D_FEAT / 4 - 1);           // float4 column, 0..1023
    const int r0  = tid >> 10;                        // row 0..511

    const f4 g1 = gates[c];
    const f4 g2 = gates[D_FEAT / 4 + c];

    size_t idx = (size_t)r0 * (D_FEAT / 4) + c;
    const size_t step = (size_t)512 * (D_FEAT / 4);

#pragma unroll 4
    for (int r = 0; r < B_SZ / 512; ++r, idx += step) {
        f4 e  = __builtin_nontemporal_load(emb + idx);
        f4 o1 = e * g1;
        f4 o2 = e * g2;
        __builtin_nontemporal_store(o1, out1 + idx);
        __builtin_nontemporal_store(o2, out2 + idx);
    }
}

extern "C" void kernel_launch(void* const* d_in, const int* in_sizes, int n_in,
                              void* d_out, int out_size, void* d_ws, size_t ws_size,
                              hipStream_t stream)
{
    const float* flat_emb = (const float*)d_in[0];
    const float* ctx1     = (const float*)d_in[1];
    const float* ctx2     = (const float*)d_in[2];
    const float* W1a      = (const float*)d_in[3];
    const float* b1a      = (const float*)d_in[4];
    const float* W2a      = (const float*)d_in[5];
    const float* b2a      = (const float*)d_in[6];
    const float* W1b      = (const float*)d_in[7];
    const float* b1b      = (const float*)d_in[8];
    const float* W2b      = (const float*)d_in[9];
    const float* b2b      = (const float*)d_in[10];

    float* out1  = (float*)d_out;
    float* out2  = (float*)d_out + (size_t)B_SZ * D_FEAT;
    float* gates = (float*)d_ws;                 // [2][D_FEAT] = 32 KB
    float* h     = (float*)d_ws + 2 * D_FEAT;    // [2][D_HID]  =  8 KB

    // A: hidden activations (tiny, 8 blocks)
    h_kernel<<<8, 256, 0, stream>>>(ctx1, ctx2, W1a, b1a, W1b, b1b, h);

    // B: gate vectors, split-K over 256 blocks (1 per CU)
    gate_kernel<<<256, 256, 0, stream>>>(W2a, b2a, W2b, b2b, h, gates);

    // C: broadcast multiply, fixed-column threads, nontemporal streaming
    mul_kernel<<<2048, 256, 0, stream>>>(
        (const f4*)flat_emb, (const f4*)gates, (f4*)out1, (f4*)out2);
}